// Round 9
// baseline (200.302 us; speedup 1.0000x reference)
//
#include <hip/hip_runtime.h>
#include <hip/hip_bf16.h>
#include <cmath>

typedef __bf16 bf16_t;
typedef __bf16 bf16x8 __attribute__((ext_vector_type(8)));
typedef float  f32x4  __attribute__((ext_vector_type(4)));

#define AS1(p) ((__attribute__((address_space(1))) void*)(p))
#define AS3(p) ((__attribute__((address_space(3))) void*)(p))

// N=8192, H=512, TAU=0.5, EPS=1e-8
// exp(x) = exp2(x * log2e / TAU); (1/0.5)*log2e = 2.885390...
#define C_EXP2 2.8853900817779268f
#define NROWS  8192
#define HDIM   512

// ---------------------------------------------------------------- f32->bf16
__global__ __launch_bounds__(256) void cvt_f32_bf16(const float* __restrict__ src,
                                                    bf16_t* __restrict__ dst, int n8) {
    int i = blockIdx.x * 256 + threadIdx.x;
    if (i >= n8) return;
    const f32x4* s4 = (const f32x4*)src;
    f32x4 a = s4[2 * (size_t)i];
    f32x4 b = s4[2 * (size_t)i + 1];
    bf16x8 o;
#pragma unroll
    for (int j = 0; j < 4; ++j) { o[j] = (bf16_t)a[j]; o[4 + j] = (bf16_t)b[j]; }
    *(bf16x8*)(dst + 8 * (size_t)i) = o;
}

// ---------------------------------------------------------------- MLP GEMM (NT)
// C[i][j] = sum_k A[i*K+k] * B[j*K+k], K=512. 128x128 tile, BK=64, NT=8,
// 2-deep dbuf, vmcnt(0)/step (proven R8 structure).
// EPI=1: bias+ELU -> bf16   EPI=2: bias -> f32 (d_out) + bf16 copy
template <int EPI>
__global__ __launch_bounds__(256, 2)
void gemm_bt(const bf16_t* __restrict__ A, const bf16_t* __restrict__ B,
             const float* __restrict__ bias,
             bf16_t* __restrict__ outb, float* __restrict__ outf) {
    constexpr int K  = 512;
    constexpr int NT = 8;
    __shared__ __align__(16) char smem[65536];

    const int tid  = threadIdx.x;
    const int lane = tid & 63;
    const int wv   = tid >> 6;
    const int wm   = wv >> 1;
    const int wn   = wv & 1;

    const long ibase = (long)blockIdx.x * 128;
    const long jbase = (long)blockIdx.y * 128;

    const int r8  = lane >> 3;
    const int c16 = lane & 7;
    const long aSrc0 = (ibase + wv * 32 + r8) * (long)K + ((c16 ^ r8) << 3);
    const long bSrc0 = (jbase + wv * 32 + r8) * (long)K + ((c16 ^ r8) << 3);

    f32x4 acc[4][4] = {};
    const int fr = lane & 15;
    const int fj = lane >> 4;
    const int crow = fj << 2;
    const int ccol = fr;

#pragma unroll
    for (int s = 0; s < 4; ++s) {
        const int ro = (wv * 32 + s * 8) * 128;
        __builtin_amdgcn_global_load_lds(AS1(A + aSrc0 + s * 8 * K), AS3(smem + ro), 16, 0, 0);
        __builtin_amdgcn_global_load_lds(AS1(B + bSrc0 + s * 8 * K), AS3(smem + 32768 + ro), 16, 0, 0);
    }
    asm volatile("s_waitcnt vmcnt(0)" ::: "memory");
    __builtin_amdgcn_s_barrier();
    asm volatile("" ::: "memory");

#pragma unroll
    for (int t = 0; t < NT; ++t) {
        if (t + 1 < NT) {
            const int nb = (t + 1) & 1;
#pragma unroll
            for (int s = 0; s < 4; ++s) {
                const int ro = (wv * 32 + s * 8) * 128;
                __builtin_amdgcn_global_load_lds(AS1(A + aSrc0 + s * 8 * K + (t + 1) * 64),
                                                 AS3(smem + nb * 16384 + ro), 16, 0, 0);
                __builtin_amdgcn_global_load_lds(AS1(B + bSrc0 + s * 8 * K + (t + 1) * 64),
                                                 AS3(smem + 32768 + nb * 16384 + ro), 16, 0, 0);
            }
        }
        asm volatile("" ::: "memory");
#pragma unroll
        for (int kk = 0; kk < 2; ++kk) {
            bf16x8 af[4], bfr[4];
#pragma unroll
            for (int m = 0; m < 4; ++m) {
                const int row = wm * 64 + m * 16 + fr;
                af[m] = *(const bf16x8*)(smem + (t & 1) * 16384 + row * 128 +
                                         (((kk * 4 + fj) ^ (fr & 7)) << 4));
            }
#pragma unroll
            for (int n = 0; n < 4; ++n) {
                const int row = wn * 64 + n * 16 + fr;
                bfr[n] = *(const bf16x8*)(smem + 32768 + (t & 1) * 16384 + row * 128 +
                                          (((kk * 4 + fj) ^ (fr & 7)) << 4));
            }
            __builtin_amdgcn_s_setprio(1);
#pragma unroll
            for (int m = 0; m < 4; ++m)
#pragma unroll
                for (int n = 0; n < 4; ++n)
                    acc[m][n] = __builtin_amdgcn_mfma_f32_16x16x32_bf16(af[m], bfr[n],
                                                                        acc[m][n], 0, 0, 0);
            __builtin_amdgcn_s_setprio(0);
        }
        asm volatile("" ::: "memory");
        if (t + 1 < NT) asm volatile("s_waitcnt vmcnt(0)" ::: "memory");
        __builtin_amdgcn_s_barrier();
        asm volatile("" ::: "memory");
    }

#pragma unroll
    for (int m = 0; m < 4; ++m) {
        const long rowb = ibase + wm * 64 + m * 16 + crow;
#pragma unroll
        for (int n = 0; n < 4; ++n) {
            const int col = (int)jbase + wn * 64 + n * 16 + ccol;
            const float bv = bias[col];
#pragma unroll
            for (int r = 0; r < 4; ++r) {
                float v = acc[m][n][r] + bv;
                const long idx = (rowb + r) * HDIM + col;
                if constexpr (EPI == 1) {
                    v = v > 0.f ? v : expm1f(v);  // ELU(alpha=1)
                    outb[idx] = (bf16_t)v;
                } else {
                    outf[idx] = v;
                    outb[idx] = (bf16_t)v;
                }
            }
        }
    }
}

// ---------------------------------------------------------------- GEMM3 + pos
// 256x128 tile, 512 threads (8 waves, 2Mx... wm=wv>>1 in 0..3, wn=wv&1),
// BK=64, NT=8, 3-DEEP staging (A 3x32K, B 3x16K = 144 KB LDS, 1 block/CU).
// 3-deep decouples stage drain from pos float: step t issues S(t+2)[6] then
// pos(t)[2]; end-of-step vmcnt(10) drains exactly S(t+1) (aged 1 phase, L2)
// and lets pos ride ~3 phases (~1500 cyc > 900 HBM latency).
// Ledger: t=0 vmcnt(8); t=1..5 vmcnt(10); t=6 vmcnt(4); t=7 none.
// Epilogue: e=exp2(acc*rn0*rn1*C) -> LDS e[256][128] f32 (overlays stage
// bufs); readers own (row group, 128B col span): 8 consecutive lanes read
// 8 consecutive f32x4 of ONE row (granules fully used); 8-lane shfl -> pS/pP.
__global__ __launch_bounds__(512, 2)
void gemm_pos(const bf16_t* __restrict__ A, const bf16_t* __restrict__ B,
              const float* __restrict__ rn0, const float* __restrict__ rn1,
              const float* __restrict__ pos,
              float* __restrict__ pS, float* __restrict__ pP) {
    constexpr int K = 512;
    // As: smem + buf*32768 (3 x 32 KB); Bs: smem + 98304 + buf*16384 (3 x 16 KB)
    __shared__ __align__(16) char smem[147456];

    const int tid  = threadIdx.x;
    const int lane = tid & 63;
    const int wv   = tid >> 6;   // 0..7
    const int wm   = wv >> 1;    // 0..3 (64-row slabs of the 256-row tile)
    const int wn   = wv & 1;     // 0..1 (64-col slabs of the 128-col tile)

    // bijective XCD swizzle (2048 blocks % 8 == 0): XCD x owns j-panels [8x,8x+8)
    const int flat = blockIdx.x;
    const int swz  = (flat & 7) * 256 + (flat >> 3);
    const long ibase = (long)(swz & 31) * 256;
    const int  jt    = swz >> 5;
    const long jbase = (long)jt * 128;

    const int r8  = lane >> 3;
    const int c16 = lane & 7;
    const long aSrc0 = (ibase + wv * 32 + r8) * (long)K + ((c16 ^ r8) << 3);
    const long bSrc0 = (jbase + wv * 16 + r8) * (long)K + ((c16 ^ r8) << 3);

    f32x4 acc[4][4] = {};
    const int fr = lane & 15;
    const int fj = lane >> 4;
    const int crow = fj << 2;
    const int ccol = fr;

    float r0v[16];
    float r1v[4];
#pragma unroll
    for (int n = 0; n < 4; ++n) r1v[n] = rn1[jbase + wn * 64 + n * 16 + ccol];
#pragma unroll
    for (int mr = 0; mr < 16; ++mr)
        r0v[mr] = rn0[ibase + wm * 64 + (mr >> 2) * 16 + crow + (mr & 3)] * C_EXP2;

    // pos ownership: chunk i -> row (tid>>3)+64*(i&3), col-chunk (tid&7)+8*(i>>2)
    f32x4 pv[16];
    const float* p00 = pos + (size_t)(ibase + (tid >> 3)) * NROWS + jbase + ((tid & 7) << 2);

    // A: 4 instr/thread (rows wv*32+s*8+r8), B: 2 instr (rows wv*16+s*8+r8)
    auto STAGE = [&](int buf, int t) {
#pragma unroll
        for (int s = 0; s < 4; ++s)
            __builtin_amdgcn_global_load_lds(AS1(A + aSrc0 + s * 8 * K + t * 64),
                                             AS3(smem + buf * 32768 + (wv * 32 + s * 8) * 128), 16, 0, 0);
#pragma unroll
        for (int s = 0; s < 2; ++s)
            __builtin_amdgcn_global_load_lds(AS1(B + bSrc0 + s * 8 * K + t * 64),
                                             AS3(smem + 98304 + buf * 16384 + (wv * 16 + s * 8) * 128), 16, 0, 0);
    };

    // ---------------- prologue: S(0), S(1); drain S(0) only (vmcnt(6) keeps S(1))
    STAGE(0, 0);
    STAGE(1, 1);
    asm volatile("s_waitcnt vmcnt(6)" ::: "memory");
    __builtin_amdgcn_s_barrier();
    asm volatile("" ::: "memory");

    // ---------------- pipelined K-loop, fully unrolled
#pragma unroll
    for (int t = 0; t < 8; ++t) {
        if (t + 2 < 8) STAGE((t + 2) % 3, t + 2);
        asm volatile("" ::: "memory");  // pin: pos(t) issues AFTER S(t+2)
#pragma unroll
        for (int h = 0; h < 2; ++h) {
            const int i = 2 * t + h;    // compile-time
            pv[i] = *(const f32x4*)(p00 + (size_t)(i & 3) * 64 * NROWS + (i >> 2) * 32);
        }
        // compute on buf t%3
#pragma unroll
        for (int kk = 0; kk < 2; ++kk) {
            bf16x8 af[4], bfr[4];
#pragma unroll
            for (int m = 0; m < 4; ++m) {
                const int row = wm * 64 + m * 16 + fr;
                af[m] = *(const bf16x8*)(smem + (t % 3) * 32768 + row * 128 +
                                         (((kk * 4 + fj) ^ (fr & 7)) << 4));
            }
#pragma unroll
            for (int n = 0; n < 4; ++n) {
                const int row = wn * 64 + n * 16 + fr;
                bfr[n] = *(const bf16x8*)(smem + 98304 + (t % 3) * 16384 + row * 128 +
                                          (((kk * 4 + fj) ^ (fr & 7)) << 4));
            }
            __builtin_amdgcn_s_setprio(1);
#pragma unroll
            for (int m = 0; m < 4; ++m)
#pragma unroll
                for (int n = 0; n < 4; ++n)
                    acc[m][n] = __builtin_amdgcn_mfma_f32_16x16x32_bf16(af[m], bfr[n],
                                                                        acc[m][n], 0, 0, 0);
            __builtin_amdgcn_s_setprio(0);
        }
        asm volatile("" ::: "memory");
        // drain exactly S(t+1); pos floats (ledger audited per step)
        if (t == 0)      asm volatile("s_waitcnt vmcnt(8)" ::: "memory");
        else if (t < 6)  asm volatile("s_waitcnt vmcnt(10)" ::: "memory");
        else if (t == 6) asm volatile("s_waitcnt vmcnt(4)" ::: "memory");
        __builtin_amdgcn_s_barrier();
        asm volatile("" ::: "memory");
    }

    // ---------------- epilogue: e -> LDS (overlays stage bufs; barrier above
    // guarantees all waves finished step-7 ds_reads)
    float* eB = (float*)smem;   // e[256][128] f32, 16B-chunk XOR swizzle by row&7
#pragma unroll
    for (int mr = 0; mr < 16; ++mr) {
        const int m = mr >> 2, r = mr & 3;
        const int row = wm * 64 + m * 16 + crow + r;   // 0..255
#pragma unroll
        for (int n = 0; n < 4; ++n) {
            const int col = wn * 64 + n * 16 + ccol;   // 0..127
            const float e = exp2f(acc[m][n][r] * r0v[mr] * r1v[n]);
            eB[row * 128 + ((((col >> 2) ^ (row & 7)) << 2) | (col & 3))] = e;
        }
    }
    asm volatile("s_waitcnt lgkmcnt(0)" ::: "memory");
    __builtin_amdgcn_s_barrier();
    asm volatile("" ::: "memory");

    float S4[4] = {0.f, 0.f, 0.f, 0.f};
    float P4[4] = {0.f, 0.f, 0.f, 0.f};
#pragma unroll
    for (int c = 0; c < 16; ++c) {
        const int rr = (tid >> 3) + 64 * (c & 3);      // 0..255
        const int cc = (tid & 7) + 8 * (c >> 2);       // 0..31
        const int slot = cc ^ (rr & 7);
        const f32x4 e4 = *(const f32x4*)&eB[rr * 128 + slot * 4];
        S4[c & 3] += e4[0] + e4[1] + e4[2] + e4[3];
        P4[c & 3] += e4[0] * pv[c][0] + e4[1] * pv[c][1] +
                     e4[2] * pv[c][2] + e4[3] * pv[c][3];
    }
#pragma unroll
    for (int a = 0; a < 4; ++a) {
#pragma unroll
        for (int off = 4; off > 0; off >>= 1) {        // 8 consecutive lanes
            S4[a] += __shfl_xor(S4[a], off);
            P4[a] += __shfl_xor(P4[a], off);
        }
    }
    if ((tid & 7) == 0) {
#pragma unroll
        for (int a = 0; a < 4; ++a) {
            const long row = ibase + (tid >> 3) + 64 * a;
            pS[(long)jt * NROWS + row] = S4[a];
            pP[(long)jt * NROWS + row] = P4[a];
        }
    }
}

// ---------------------------------------------------------------- row norms
__global__ __launch_bounds__(256) void rownorm(const bf16_t* __restrict__ Z,
                                               float* __restrict__ rn) {
    const int row  = blockIdx.x * 4 + (threadIdx.x >> 6);
    const int lane = threadIdx.x & 63;
    bf16x8 v = *(const bf16x8*)&Z[(size_t)row * HDIM + lane * 8];
    float s = 0.f;
#pragma unroll
    for (int j = 0; j < 8; ++j) { float f = (float)v[j]; s += f * f; }
#pragma unroll
    for (int off = 32; off > 0; off >>= 1) s += __shfl_xor(s, off);
    if (lane == 0) rn[row] = rsqrtf(s);
}

// ---------------------------------------------------------------- reductions
__global__ __launch_bounds__(256) void reduce_rows(const float* __restrict__ pS,
                                                   const float* __restrict__ pP,
                                                   float* __restrict__ bsum) {
    const int i = blockIdx.x * 256 + threadIdx.x;  // row 0..8191
    float S = 0.f, P = 0.f;
    for (int jb = 0; jb < 64; ++jb) {
        S += pS[jb * NROWS + i];
        P += pP[jb * NROWS + i];
    }
    float t = logf(P / (S + 1e-8f) + 1e-8f);
#pragma unroll
    for (int off = 32; off > 0; off >>= 1) t += __shfl_xor(t, off);
    __shared__ float red[4];
    if ((threadIdx.x & 63) == 0) red[threadIdx.x >> 6] = t;
    __syncthreads();
    if (threadIdx.x == 0) bsum[blockIdx.x] = red[0] + red[1] + red[2] + red[3];
}

__global__ void finalize(const float* __restrict__ bsum, float* __restrict__ loss) {
    float t = (threadIdx.x < 32) ? bsum[threadIdx.x] : 0.f;
#pragma unroll
    for (int off = 32; off > 0; off >>= 1) t += __shfl_xor(t, off);
    if (threadIdx.x == 0) *loss = -(t * (1.0f / 8192.0f));
}

// ---------------------------------------------------------------- launch
extern "C" void kernel_launch(void* const* d_in, const int* in_sizes, int n_in,
                              void* d_out, int out_size, void* d_ws, size_t ws_size,
                              hipStream_t stream) {
    const float* embd0 = (const float*)d_in[0];
    const float* embd1 = (const float*)d_in[1];
    const float* pos   = (const float*)d_in[2];
    const float* W1    = (const float*)d_in[3];
    const float* b1    = (const float*)d_in[4];
    const float* W2    = (const float*)d_in[5];
    const float* b2    = (const float*)d_in[6];
    float* out = (float*)d_out;  // [z0 | z1 | loss]

    char* ws = (char*)d_ws;
    bf16_t* Xb   = (bf16_t*)(ws);               // 16 MB  [16384][512]
    bf16_t* Hb   = (bf16_t*)(ws + 16777216);    // 16 MB
    bf16_t* Zb   = (bf16_t*)(ws + 33554432);    // 16 MB
    bf16_t* W1b  = (bf16_t*)(ws + 50331648);    // 512 KB
    bf16_t* W2b  = (bf16_t*)(ws + 50855936);    // 512 KB
    float*  rn   = (float*)(ws + 51380224);     // 64 KB (rn0|rn1)
    float*  pS   = (float*)(ws + 51445760);     // 2 MB [64][8192]
    float*  pP   = (float*)(ws + 53542912);     // 2 MB
    float*  bsum = (float*)(ws + 55640064);     // 128 B

    cvt_f32_bf16<<<2048, 256, 0, stream>>>(embd0, Xb, 524288);
    cvt_f32_bf16<<<2048, 256, 0, stream>>>(embd1, Xb + 4194304, 524288);
    cvt_f32_bf16<<<128, 256, 0, stream>>>(W1, W1b, 32768);
    cvt_f32_bf16<<<128, 256, 0, stream>>>(W2, W2b, 32768);

    gemm_bt<1><<<dim3(128, 4), 256, 0, stream>>>(Xb, W1b, b1, Hb, nullptr);
    gemm_bt<2><<<dim3(128, 4), 256, 0, stream>>>(Hb, W2b, b2, Zb, out);
    rownorm<<<4096, 256, 0, stream>>>(Zb, rn);
    gemm_pos<<<2048, 512, 0, stream>>>(Zb, Zb + 4194304, rn, rn + NROWS, pos, pS, pP);
    reduce_rows<<<32, 256, 0, stream>>>(pS, pP, bsum);
    finalize<<<1, 64, 0, stream>>>(bsum, out + 8388608);
}

// Round 10
// 196.274 us; speedup vs baseline: 1.0205x; 1.0205x over previous
//
#include <hip/hip_runtime.h>
#include <hip/hip_bf16.h>
#include <cmath>

typedef __bf16 bf16_t;
typedef __bf16 bf16x8 __attribute__((ext_vector_type(8)));
typedef float  f32x4  __attribute__((ext_vector_type(4)));

#define AS1(p) ((__attribute__((address_space(1))) void*)(p))
#define AS3(p) ((__attribute__((address_space(3))) void*)(p))

// N=8192, H=512, TAU=0.5, EPS=1e-8
// exp(x) = exp2(x * log2e / TAU); (1/0.5)*log2e = 2.885390...
#define C_EXP2 2.8853900817779268f
#define NROWS  8192
#define HDIM   512

// ---------------------------------------------------------------- f32->bf16
__global__ __launch_bounds__(256) void cvt_f32_bf16(const float* __restrict__ src,
                                                    bf16_t* __restrict__ dst, int n8) {
    int i = blockIdx.x * 256 + threadIdx.x;
    if (i >= n8) return;
    const f32x4* s4 = (const f32x4*)src;
    f32x4 a = s4[2 * (size_t)i];
    f32x4 b = s4[2 * (size_t)i + 1];
    bf16x8 o;
#pragma unroll
    for (int j = 0; j < 4; ++j) { o[j] = (bf16_t)a[j]; o[4 + j] = (bf16_t)b[j]; }
    *(bf16x8*)(dst + 8 * (size_t)i) = o;
}

// ---------------------------------------------------------------- MLP GEMM (NT)
// 128x128 tile, BK=64, NT=8, 2-deep dbuf, vmcnt(0)/step (proven R8 structure).
// EPI=1: bias+ELU -> bf16   EPI=2: bias -> f32 (d_out) + bf16 copy
template <int EPI>
__global__ __launch_bounds__(256, 2)
void gemm_bt(const bf16_t* __restrict__ A, const bf16_t* __restrict__ B,
             const float* __restrict__ bias,
             bf16_t* __restrict__ outb, float* __restrict__ outf) {
    constexpr int K  = 512;
    constexpr int NT = 8;
    __shared__ __align__(16) char smem[65536];

    const int tid  = threadIdx.x;
    const int lane = tid & 63;
    const int wv   = tid >> 6;
    const int wm   = wv >> 1;
    const int wn   = wv & 1;

    const long ibase = (long)blockIdx.x * 128;
    const long jbase = (long)blockIdx.y * 128;

    const int r8  = lane >> 3;
    const int c16 = lane & 7;
    const long aSrc0 = (ibase + wv * 32 + r8) * (long)K + ((c16 ^ r8) << 3);
    const long bSrc0 = (jbase + wv * 32 + r8) * (long)K + ((c16 ^ r8) << 3);

    f32x4 acc[4][4] = {};
    const int fr = lane & 15;
    const int fj = lane >> 4;
    const int crow = fj << 2;
    const int ccol = fr;

#pragma unroll
    for (int s = 0; s < 4; ++s) {
        const int ro = (wv * 32 + s * 8) * 128;
        __builtin_amdgcn_global_load_lds(AS1(A + aSrc0 + s * 8 * K), AS3(smem + ro), 16, 0, 0);
        __builtin_amdgcn_global_load_lds(AS1(B + bSrc0 + s * 8 * K), AS3(smem + 32768 + ro), 16, 0, 0);
    }
    asm volatile("s_waitcnt vmcnt(0)" ::: "memory");
    __builtin_amdgcn_s_barrier();
    asm volatile("" ::: "memory");

#pragma unroll
    for (int t = 0; t < NT; ++t) {
        if (t + 1 < NT) {
            const int nb = (t + 1) & 1;
#pragma unroll
            for (int s = 0; s < 4; ++s) {
                const int ro = (wv * 32 + s * 8) * 128;
                __builtin_amdgcn_global_load_lds(AS1(A + aSrc0 + s * 8 * K + (t + 1) * 64),
                                                 AS3(smem + nb * 16384 + ro), 16, 0, 0);
                __builtin_amdgcn_global_load_lds(AS1(B + bSrc0 + s * 8 * K + (t + 1) * 64),
                                                 AS3(smem + 32768 + nb * 16384 + ro), 16, 0, 0);
            }
        }
        asm volatile("" ::: "memory");
#pragma unroll
        for (int kk = 0; kk < 2; ++kk) {
            bf16x8 af[4], bfr[4];
#pragma unroll
            for (int m = 0; m < 4; ++m) {
                const int row = wm * 64 + m * 16 + fr;
                af[m] = *(const bf16x8*)(smem + (t & 1) * 16384 + row * 128 +
                                         (((kk * 4 + fj) ^ (fr & 7)) << 4));
            }
#pragma unroll
            for (int n = 0; n < 4; ++n) {
                const int row = wn * 64 + n * 16 + fr;
                bfr[n] = *(const bf16x8*)(smem + 32768 + (t & 1) * 16384 + row * 128 +
                                          (((kk * 4 + fj) ^ (fr & 7)) << 4));
            }
            __builtin_amdgcn_s_setprio(1);
#pragma unroll
            for (int m = 0; m < 4; ++m)
#pragma unroll
                for (int n = 0; n < 4; ++n)
                    acc[m][n] = __builtin_amdgcn_mfma_f32_16x16x32_bf16(af[m], bfr[n],
                                                                        acc[m][n], 0, 0, 0);
            __builtin_amdgcn_s_setprio(0);
        }
        asm volatile("" ::: "memory");
        if (t + 1 < NT) asm volatile("s_waitcnt vmcnt(0)" ::: "memory");
        __builtin_amdgcn_s_barrier();
        asm volatile("" ::: "memory");
    }

#pragma unroll
    for (int m = 0; m < 4; ++m) {
        const long rowb = ibase + wm * 64 + m * 16 + crow;
#pragma unroll
        for (int n = 0; n < 4; ++n) {
            const int col = (int)jbase + wn * 64 + n * 16 + ccol;
            const float bv = bias[col];
#pragma unroll
            for (int r = 0; r < 4; ++r) {
                float v = acc[m][n][r] + bv;
                const long idx = (rowb + r) * HDIM + col;
                if constexpr (EPI == 1) {
                    v = v > 0.f ? v : expm1f(v);  // ELU(alpha=1)
                    outb[idx] = (bf16_t)v;
                } else {
                    outf[idx] = v;
                    outb[idx] = (bf16_t)v;
                }
            }
        }
    }
}

// ---------------------------------------------------------------- GEMM3 + pos
// 256(i) x 128(j) tile, 512 threads = 8 waves (wi 0..3 x wj 0..1), BK=64,
// NT=8, 3-deep staging (A 3x32K + B 3x16K = 144 KB LDS).
// SWAPPED MFMA: acc[mi][nj] = mfma(bfr[nj], af[mi], .) so D col(lane&15)=i,
// D row(reg)=j -> each lane holds 4 CONSECUTIVE j. pos is loaded as one
// f32x4 per fragment in exactly the consumed layout (16 rows x 64B/instr,
// nj-pairs complete 128B granules) -> NO e-LDS materialization at all.
// Ledger (audited, = R9): prologue vmcnt(6); t0 vmcnt(8); t1-5 vmcnt(10)
// (drains S(t+1), pv rides 2 steps); t6 vmcnt(4); t7 none (compiler waits
// pv before epilogue use). Epilogue: exp2+FMA in regs, shfl_xor(16,32) over
// the fj groups, 4 KB LDS combine across wj (overlays buf0, dead after t6).
__global__ __launch_bounds__(512, 1)
void gemm_pos(const bf16_t* __restrict__ A, const bf16_t* __restrict__ B,
              const float* __restrict__ rn0, const float* __restrict__ rn1,
              const float* __restrict__ pos,
              float* __restrict__ pS, float* __restrict__ pP) {
    constexpr int K = 512;
    // As: smem + buf*32768 (3 x 32 KB); Bs: smem + 98304 + buf*16384 (3 x 16 KB)
    __shared__ __align__(16) char smem[147456];

    const int tid  = threadIdx.x;
    const int lane = tid & 63;
    const int wv   = tid >> 6;   // 0..7
    const int wi   = wv >> 1;    // 0..3: 64-row (i) slab
    const int wj   = wv & 1;     // 0..1: 64-col (j) slab

    // bijective XCD swizzle (2048 blocks % 8 == 0)
    const int flat = blockIdx.x;
    const int swz  = (flat & 7) * 256 + (flat >> 3);
    const long ibase = (long)(swz & 31) * 256;
    const int  jt    = swz >> 5;
    const long jbase = (long)jt * 128;

    const int r8  = lane >> 3;
    const int c16 = lane & 7;
    const long aSrc0 = (ibase + wv * 32 + r8) * (long)K + ((c16 ^ r8) << 3);
    const long bSrc0 = (jbase + wv * 16 + r8) * (long)K + ((c16 ^ r8) << 3);

    f32x4 acc[4][4] = {};
    const int fr = lane & 15;   // i within 16 (C col after swap)
    const int fj = lane >> 4;
    const int crow = fj << 2;   // j base within fragment
    const int ccol = fr;

    // scales: r0 per i (4 regs), r1 per j (16 regs) — issued BEFORE staging,
    // drained by the prologue vmcnt(6)
    float r0v[4], r1v[16];
#pragma unroll
    for (int mi = 0; mi < 4; ++mi)
        r0v[mi] = rn0[ibase + wi * 64 + mi * 16 + ccol] * C_EXP2;
#pragma unroll
    for (int nj = 0; nj < 4; ++nj)
#pragma unroll
        for (int r = 0; r < 4; ++r)
            r1v[nj * 4 + r] = rn1[jbase + wj * 64 + nj * 16 + crow + r];

    f32x4 pv[4][4];  // pos in fragment layout: pv[mi][nj] = pos[i][j..j+3]
    const float* p00 = pos + (size_t)(ibase + wi * 64 + ccol) * NROWS + jbase + wj * 64 + crow;

    auto STAGE = [&](int buf, int t) {
#pragma unroll
        for (int s = 0; s < 4; ++s)
            __builtin_amdgcn_global_load_lds(AS1(A + aSrc0 + s * 8 * K + t * 64),
                                             AS3(smem + buf * 32768 + (wv * 32 + s * 8) * 128), 16, 0, 0);
#pragma unroll
        for (int s = 0; s < 2; ++s)
            __builtin_amdgcn_global_load_lds(AS1(B + bSrc0 + s * 8 * K + t * 64),
                                             AS3(smem + 98304 + buf * 16384 + (wv * 16 + s * 8) * 128), 16, 0, 0);
    };

    // ---------------- prologue: S(0), S(1); drain rn + S(0), keep S(1)
    STAGE(0, 0);
    STAGE(1, 1);
    asm volatile("s_waitcnt vmcnt(6)" ::: "memory");
    __builtin_amdgcn_s_barrier();
    asm volatile("" ::: "memory");

    // ---------------- pipelined K-loop, fully unrolled
#pragma unroll
    for (int t = 0; t < 8; ++t) {
        if (t + 2 < 8) STAGE((t + 2) % 3, t + 2);
        asm volatile("" ::: "memory");  // pin: pv pair issues AFTER S(t+2)
        {
            const int mi = t >> 1, njb = (t & 1) * 2;   // compile-time
            pv[mi][njb]     = *(const f32x4*)(p00 + (size_t)(mi * 16) * NROWS + njb * 16);
            pv[mi][njb + 1] = *(const f32x4*)(p00 + (size_t)(mi * 16) * NROWS + (njb + 1) * 16);
        }
        // compute on buf t%3
#pragma unroll
        for (int kk = 0; kk < 2; ++kk) {
            bf16x8 af[4], bfr[4];
#pragma unroll
            for (int mi = 0; mi < 4; ++mi) {
                const int row = wi * 64 + mi * 16 + fr;
                af[mi] = *(const bf16x8*)(smem + (t % 3) * 32768 + row * 128 +
                                          (((kk * 4 + fj) ^ (fr & 7)) << 4));
            }
#pragma unroll
            for (int nj = 0; nj < 4; ++nj) {
                const int row = wj * 64 + nj * 16 + fr;
                bfr[nj] = *(const bf16x8*)(smem + 98304 + (t % 3) * 16384 + row * 128 +
                                           (((kk * 4 + fj) ^ (fr & 7)) << 4));
            }
            __builtin_amdgcn_s_setprio(1);
#pragma unroll
            for (int mi = 0; mi < 4; ++mi)
#pragma unroll
                for (int nj = 0; nj < 4; ++nj)
                    acc[mi][nj] = __builtin_amdgcn_mfma_f32_16x16x32_bf16(bfr[nj], af[mi],
                                                                          acc[mi][nj], 0, 0, 0);
            __builtin_amdgcn_s_setprio(0);
        }
        asm volatile("" ::: "memory");
        if (t + 1 < 8) {
            // drain exactly S(t+1); pv floats ~2 steps
            if (t == 0)      asm volatile("s_waitcnt vmcnt(8)" ::: "memory");
            else if (t < 6)  asm volatile("s_waitcnt vmcnt(10)" ::: "memory");
            else             asm volatile("s_waitcnt vmcnt(4)" ::: "memory");
            __builtin_amdgcn_s_barrier();
            asm volatile("" ::: "memory");
        }
    }

    // ---------------- epilogue: pure-register e, then tiny cross-wj combine
    float S[4] = {0.f, 0.f, 0.f, 0.f};
    float P[4] = {0.f, 0.f, 0.f, 0.f};
#pragma unroll
    for (int mi = 0; mi < 4; ++mi)
#pragma unroll
        for (int nj = 0; nj < 4; ++nj)
#pragma unroll
            for (int r = 0; r < 4; ++r) {
                const float e = exp2f(acc[mi][nj][r] * r0v[mi] * r1v[nj * 4 + r]);
                S[mi] += e;
                P[mi] += e * pv[mi][nj][r];
            }
#pragma unroll
    for (int mi = 0; mi < 4; ++mi) {   // reduce over the 4 fj groups (same i)
        S[mi] += __shfl_xor(S[mi], 16); S[mi] += __shfl_xor(S[mi], 32);
        P[mi] += __shfl_xor(P[mi], 16); P[mi] += __shfl_xor(P[mi], 32);
    }
    // combine the two wj waves: 4 KB scratch overlays buf0-A (dead since the
    // end-of-t6 barrier; t7 reads buf1 only)
    float* sc = (float*)smem;          // [S: wj0 256 | wj1 256 | P: wj0 256 | wj1 256]
    if (lane < 16) {
#pragma unroll
        for (int mi = 0; mi < 4; ++mi) {
            sc[wj * 256 + wi * 64 + mi * 16 + lane] = S[mi];
            sc[512 + wj * 256 + wi * 64 + mi * 16 + lane] = P[mi];
        }
    }
    __syncthreads();
    if (tid < 256) {
        pS[(long)jt * NROWS + ibase + tid] = sc[tid] + sc[256 + tid];
        pP[(long)jt * NROWS + ibase + tid] = sc[512 + tid] + sc[768 + tid];
    }
}

// ---------------------------------------------------------------- row norms
__global__ __launch_bounds__(256) void rownorm(const bf16_t* __restrict__ Z,
                                               float* __restrict__ rn) {
    const int row  = blockIdx.x * 4 + (threadIdx.x >> 6);
    const int lane = threadIdx.x & 63;
    bf16x8 v = *(const bf16x8*)&Z[(size_t)row * HDIM + lane * 8];
    float s = 0.f;
#pragma unroll
    for (int j = 0; j < 8; ++j) { float f = (float)v[j]; s += f * f; }
#pragma unroll
    for (int off = 32; off > 0; off >>= 1) s += __shfl_xor(s, off);
    if (lane == 0) rn[row] = rsqrtf(s);
}

// ---------------------------------------------------------------- reductions
__global__ __launch_bounds__(256) void reduce_rows(const float* __restrict__ pS,
                                                   const float* __restrict__ pP,
                                                   float* __restrict__ bsum) {
    const int i = blockIdx.x * 256 + threadIdx.x;  // row 0..8191
    float S = 0.f, P = 0.f;
    for (int jb = 0; jb < 64; ++jb) {
        S += pS[jb * NROWS + i];
        P += pP[jb * NROWS + i];
    }
    float t = logf(P / (S + 1e-8f) + 1e-8f);
#pragma unroll
    for (int off = 32; off > 0; off >>= 1) t += __shfl_xor(t, off);
    __shared__ float red[4];
    if ((threadIdx.x & 63) == 0) red[threadIdx.x >> 6] = t;
    __syncthreads();
    if (threadIdx.x == 0) bsum[blockIdx.x] = red[0] + red[1] + red[2] + red[3];
}

__global__ void finalize(const float* __restrict__ bsum, float* __restrict__ loss) {
    float t = (threadIdx.x < 32) ? bsum[threadIdx.x] : 0.f;
#pragma unroll
    for (int off = 32; off > 0; off >>= 1) t += __shfl_xor(t, off);
    if (threadIdx.x == 0) *loss = -(t * (1.0f / 8192.0f));
}

// ---------------------------------------------------------------- launch
extern "C" void kernel_launch(void* const* d_in, const int* in_sizes, int n_in,
                              void* d_out, int out_size, void* d_ws, size_t ws_size,
                              hipStream_t stream) {
    const float* embd0 = (const float*)d_in[0];
    const float* embd1 = (const float*)d_in[1];
    const float* pos   = (const float*)d_in[2];
    const float* W1    = (const float*)d_in[3];
    const float* b1    = (const float*)d_in[4];
    const float* W2    = (const float*)d_in[5];
    const float* b2    = (const float*)d_in[6];
    float* out = (float*)d_out;  // [z0 | z1 | loss]

    char* ws = (char*)d_ws;
    bf16_t* Xb   = (bf16_t*)(ws);               // 16 MB  [16384][512]
    bf16_t* Hb   = (bf16_t*)(ws + 16777216);    // 16 MB
    bf16_t* Zb   = (bf16_t*)(ws + 33554432);    // 16 MB
    bf16_t* W1b  = (bf16_t*)(ws + 50331648);    // 512 KB
    bf16_t* W2b  = (bf16_t*)(ws + 50855936);    // 512 KB
    float*  rn   = (float*)(ws + 51380224);     // 64 KB (rn0|rn1)
    float*  pS   = (float*)(ws + 51445760);     // 2 MB [64][8192]
    float*  pP   = (float*)(ws + 53542912);     // 2 MB
    float*  bsum = (float*)(ws + 55640064);     // 128 B

    cvt_f32_bf16<<<2048, 256, 0, stream>>>(embd0, Xb, 524288);
    cvt_f32_bf16<<<2048, 256, 0, stream>>>(embd1, Xb + 4194304, 524288);
    cvt_f32_bf16<<<128, 256, 0, stream>>>(W1, W1b, 32768);
    cvt_f32_bf16<<<128, 256, 0, stream>>>(W2, W2b, 32768);

    gemm_bt<1><<<dim3(128, 4), 256, 0, stream>>>(Xb, W1b, b1, Hb, nullptr);
    gemm_bt<2><<<dim3(128, 4), 256, 0, stream>>>(Hb, W2b, b2, Zb, out);
    rownorm<<<4096, 256, 0, stream>>>(Zb, rn);
    gemm_pos<<<2048, 512, 0, stream>>>(Zb, Zb + 4194304, rn, rn + NROWS, pos, pS, pP);
    reduce_rows<<<32, 256, 0, stream>>>(pS, pP, bsum);
    finalize<<<1, 64, 0, stream>>>(bsum, out + 8388608);
}